// Round 9
// baseline (11734.318 us; speedup 1.0000x reference)
//
#include <hip/hip_runtime.h>

#define CC 256
#define HW 3136
#define WW 56
#define K3 768

typedef unsigned short u16;

__device__ __forceinline__ float bf2f(u16 u) {
    union { unsigned int i; float f; } c; c.i = ((unsigned int)u) << 16; return c.f;
}

// ---------------------------------------------------------------------------
// Naive t7: t7t[b][c2][kg] = p7[kg,c2]/56 * sum_p t2[kg,p] * x[b,c2,p]
//   t2[3*c1+tap] sources channel (c1-1)%C   (np.roll(+1) standard semantics)
//   F32 workspace now.
// ---------------------------------------------------------------------------
__launch_bounds__(256)
__global__ void n1_t7(const float* __restrict__ x, const float* __restrict__ p7w,
                      float* __restrict__ t7t) {
    const int kg = blockIdx.x;
    const int b  = blockIdx.y;
    const int c2 = threadIdx.x;
    const int c1 = kg / 3, tap = kg - 3 * c1;
    const int off = 2 * tap - 2;
    const int srcc = (c1 == 0) ? (CC - 1) : (c1 - 1);   // roll(+1)
    const float* t2row = x + ((size_t)b * CC + srcc) * HW;
    const float* xrow  = x + ((size_t)b * CC + c2) * HW;

    float s = 0.f;
    for (int h = 0; h < WW; ++h) {
        const float* t2r = t2row + h * WW;
        const float* xr  = xrow + h * WW;
        #pragma unroll 8
        for (int w = 0; w < WW; ++w) {
            int wo = w + off;
            float t2v = ((unsigned)wo < (unsigned)WW) ? t2r[wo] : 0.f;
            s = fmaf(t2v, xr[w], s);
        }
    }
    t7t[((size_t)b * CC + c2) * K3 + kg] = (s * (1.0f / 56.0f)) * p7w[kg * CC + c2];
}

// ---------------------------------------------------------------------------
// Naive fused t3 + out, per (b, image-row h):
//   phase 1: t3f[o][w] = sum_k W3[o,k] * t1[k, h*56+w]      (f32, LDS)
//   phase 2: out[c2][p] = (1/sqrt(768)) * sum_k t7[k,c2] *
//                         max(t3f[k/3][w], sin(pi/2 * x[k/3, p+off(k%3)]))
//   F32 OUTPUT WRITES (d_out is float32 per reference output dtype).
// ---------------------------------------------------------------------------
__launch_bounds__(256)
__global__ void n2_out(const float* __restrict__ x, const float* __restrict__ w3,
                       const float* __restrict__ t7t, float* __restrict__ out) {
    const int hrow = blockIdx.x;      // 0..55, p-tile = one image row
    const int b    = blockIdx.y;
    const int tid  = threadIdx.x;
    const int p0   = hrow * WW;

    __shared__ float t3f[CC][WW + 1];   // 58.4 KB
    __shared__ float t6col[K3];         // 3 KB

    const float* xb = x + (size_t)b * CC * HW;

    // ---- phase 1: thread o = tid computes t3 for its row, all 56 w ----
    {
        const float* w3row = w3 + (size_t)tid * K3;
        float acc[WW];
        #pragma unroll
        for (int i = 0; i < WW; ++i) acc[i] = 0.f;
        for (int c1 = 0; c1 < CC; ++c1) {
            const float* xr = xb + (size_t)c1 * HW + p0;
            #pragma unroll
            for (int tap = 0; tap < 3; ++tap) {
                float w3v = w3row[c1 * 3 + tap];
                int off = 2 * tap - 2;
                #pragma unroll
                for (int pl = 0; pl < WW; ++pl) {
                    int wo = pl + off;
                    float xv = ((unsigned)wo < (unsigned)WW) ? xr[wo] : 0.f;
                    acc[pl] = fmaf(w3v, xv, acc[pl]);
                }
            }
        }
        #pragma unroll
        for (int pl = 0; pl < WW; ++pl) t3f[tid][pl] = acc[pl];
    }
    __syncthreads();

    const float* t7row = t7t + ((size_t)b * CC + tid) * K3;
    const float sc = 0.03608439182435161f;   // 1/sqrt(768)

    for (int pl = 0; pl < WW; ++pl) {
        // step A: cooperative t6 column (c1 = tid, 3 taps each)
        {
            const float* xr = xb + (size_t)tid * HW + p0;
            float t3v = t3f[tid][pl];
            #pragma unroll
            for (int tap = 0; tap < 3; ++tap) {
                int wo = pl + 2 * tap - 2;
                float xv = ((unsigned)wo < (unsigned)WW) ? xr[wo] : 0.f;
                float t4v = sinf(1.5707963f * xv);
                t6col[tid * 3 + tap] = fmaxf(t3v, t4v);
            }
        }
        __syncthreads();
        // step B: thread c2 = tid dots t7 row with t6 column
        float s = 0.f;
        for (int kg = 0; kg < K3; kg += 4) {
            const float4 v = *(const float4*)(t7row + kg);
            s = fmaf(v.x, t6col[kg + 0], s);
            s = fmaf(v.y, t6col[kg + 1], s);
            s = fmaf(v.z, t6col[kg + 2], s);
            s = fmaf(v.w, t6col[kg + 3], s);
        }
        out[((size_t)b * CC + tid) * HW + p0 + pl] = s * sc;
        __syncthreads();
    }
}

extern "C" void kernel_launch(void* const* d_in, const int* in_sizes, int n_in,
                              void* d_out, int out_size, void* d_ws, size_t ws_size,
                              hipStream_t stream) {
    const float* x   = (const float*)d_in[0];   // (16,256,56,56) f32
    const float* w3  = (const float*)d_in[1];   // (256,768) f32  (dict order)
    const float* p7  = (const float*)d_in[2];   // (1,256,3,256) f32
    float* out = (float*)d_out;                 // FLOAT32 output (reference dtype)

    float* t7t = (float*)d_ws;                  // 16*256*768 f32 = 12.6 MB

    n1_t7<<<dim3(K3, 16), 256, 0, stream>>>(x, p7, t7t);
    n2_out<<<dim3(WW, 16), 256, 0, stream>>>(x, w3, t7t, out);
}

// Round 10
// 567.899 us; speedup vs baseline: 20.6627x; 20.6627x over previous
//
#include <hip/hip_runtime.h>
#include <hip/hip_bf16.h>

#define NB 16
#define CC 256
#define HW 3136
#define WW 56
#define K3 768
#define PT 64            // p-tile of fused kernel (3136 = 49*64)
#define T3S (PT + 1)     // t3 LDS row stride

typedef __attribute__((ext_vector_type(8))) short short8;
typedef __attribute__((ext_vector_type(4))) float f32x4;
typedef unsigned short u16;

__device__ __forceinline__ u16 f2bf(float f) {
    union { float f; unsigned int i; } c; c.f = f;
    unsigned int u = c.i;
    u += 0x7fffu + ((u >> 16) & 1u);   // RNE
    return (u16)(u >> 16);
}
__device__ __forceinline__ float bf2f(u16 u) {
    union { unsigned int i; float f; } c; c.i = ((unsigned int)u) << 16; return c.f;
}

// ---------------------------------------------------------------------------
// Kernel 1: t7t[b][c2][k] = p7[k][c2] * (1/56) * sum_p t2[k,p] * x[c2,p]
//   t2[k=3*c1+tap, p] = x[(c1-1)%C, p+off(tap)]  (off = 2*tap-2, zero OOB in w)
//   GEMM M=768(k) N=256(c2) K=3136(p), both operands p-major.
// ---------------------------------------------------------------------------
__launch_bounds__(256)
__global__ void k1_t7(const float* __restrict__ x, const float* __restrict__ p7w,
                      u16* __restrict__ t7t) {
    const int m0 = blockIdx.x * 128;   // k-tile
    const int n0 = blockIdx.y * 128;   // c2-tile
    const int b  = blockIdx.z;
    const int t = threadIdx.x, lane = t & 63, wid = t >> 6;
    const int wm = wid >> 1, wn = wid & 1;

    __shared__ __align__(16) u16 lsA[128 * 40];
    __shared__ __align__(16) u16 lsB[128 * 40];

    const float* xb = x + (size_t)b * CC * HW;
    f32x4 acc[4][4] = {};

    for (int p0 = 0; p0 < HW; p0 += 32) {
        #pragma unroll
        for (int cc = 0; cc < 2; ++cc) {
            int ch = t + cc * 256;
            int krow = ch >> 2, pc = ch & 3;
            int kg = m0 + krow;
            int c1 = kg / 3;
            int tap = kg - c1 * 3;
            int off = 2 * tap - 2;
            int srcc = (c1 == 0) ? (CC - 1) : (c1 - 1);   // roll(+1)
            const float* xr = xb + (size_t)srcc * HW;
            int pb = p0 + pc * 8;
            short8 sv;
            #pragma unroll
            for (int j = 0; j < 8; ++j) {
                int p = pb + j;
                int w = p % WW;
                float xv = ((unsigned)(w + off) < (unsigned)WW) ? xr[p + off] : 0.0f;
                sv[j] = (short)f2bf(xv);
            }
            *(short8*)&lsA[krow * 40 + pc * 8] = sv;
        }
        #pragma unroll
        for (int cc = 0; cc < 2; ++cc) {
            int ch = t + cc * 256;
            int crow = ch >> 2, pc = ch & 3;
            const float4* src = (const float4*)(xb + (size_t)(n0 + crow) * HW + p0 + pc * 8);
            float4 v0 = src[0], v1 = src[1];
            short8 sv;
            sv[0] = (short)f2bf(v0.x); sv[1] = (short)f2bf(v0.y);
            sv[2] = (short)f2bf(v0.z); sv[3] = (short)f2bf(v0.w);
            sv[4] = (short)f2bf(v1.x); sv[5] = (short)f2bf(v1.y);
            sv[6] = (short)f2bf(v1.z); sv[7] = (short)f2bf(v1.w);
            *(short8*)&lsB[crow * 40 + pc * 8] = sv;
        }
        __syncthreads();
        short8 af[4], bfr[4];
        #pragma unroll
        for (int i = 0; i < 4; ++i)
            af[i] = *(const short8*)&lsA[(wm * 64 + i * 16 + (lane & 15)) * 40 + (lane >> 4) * 8];
        #pragma unroll
        for (int j = 0; j < 4; ++j)
            bfr[j] = *(const short8*)&lsB[(wn * 64 + j * 16 + (lane & 15)) * 40 + (lane >> 4) * 8];
        #pragma unroll
        for (int i = 0; i < 4; ++i)
            #pragma unroll
            for (int j = 0; j < 4; ++j)
                acc[i][j] = __builtin_amdgcn_mfma_f32_16x16x32_bf16(af[i], bfr[j], acc[i][j], 0, 0, 0);
        __syncthreads();
    }

    const float s = 1.0f / 56.0f;
    #pragma unroll
    for (int i = 0; i < 4; ++i) {
        int kg0 = m0 + wm * 64 + i * 16 + ((lane >> 4) << 2);
        #pragma unroll
        for (int j = 0; j < 4; ++j) {
            int c2 = n0 + wn * 64 + j * 16 + (lane & 15);
            #pragma unroll
            for (int r = 0; r < 4; ++r) {
                int kg = kg0 + r;
                float v = acc[i][j][r] * s * p7w[kg * 256 + c2];
                t7t[((size_t)b * CC + c2) * K3 + kg] = f2bf(v);
            }
        }
    }
}

// ---------------------------------------------------------------------------
// Fused kernel 2+3 per (b, 64-wide p-tile):
//   phase 1: t3t[c1][p] = sum_k W3[c1,k] t1[k,p]   (LDS, bf16)
//   phase 2: out[c2][p] = (1/sqrt(768)) * sum_k t7t[c2][k] *
//                         max(t3t[k/3][p], sin(pi/2 * x[k/3, p+off(k%3)]))
//   OUTPUT IS FLOAT32.
// ---------------------------------------------------------------------------
__launch_bounds__(256)
__global__ void k23_fused(const float* __restrict__ x, const float* __restrict__ w3,
                          const u16* __restrict__ t7t, float* __restrict__ out) {
    const int p0 = blockIdx.x * PT;
    const int b  = blockIdx.y;
    const int t = threadIdx.x, lane = t & 63, wid = t >> 6;
    const int l15 = lane & 15, l16 = lane >> 4;

    __shared__ __align__(16) u16 t3t[CC * T3S];    // 33.3 KB  [c1][p]
    __shared__ __align__(16) u16 lsA[CC * 40];     // 20.5 KB
    __shared__ __align__(16) u16 lsB[PT * 40];     //  5.1 KB

    const float* xb = x + (size_t)b * CC * HW;
    const int kl = t & 31, pg = t >> 5;

    f32x4 acc[4][4];

    // ---------------- phase 1: t3 tile ----------------
    #pragma unroll
    for (int i = 0; i < 4; ++i)
        #pragma unroll
        for (int j = 0; j < 4; ++j)
            acc[i][j] = (f32x4){0.f, 0.f, 0.f, 0.f};

    for (int k0 = 0; k0 < K3; k0 += 32) {
        // stage A: W3 (256 rows x 32 k), f32->bf16
        #pragma unroll
        for (int cc = 0; cc < 4; ++cc) {
            int ch = t + cc * 256;
            int orow = ch >> 2, kc = ch & 3;
            const float4* src = (const float4*)(w3 + (size_t)orow * K3 + k0 + kc * 8);
            float4 v0 = src[0], v1 = src[1];
            short8 sv;
            sv[0] = (short)f2bf(v0.x); sv[1] = (short)f2bf(v0.y);
            sv[2] = (short)f2bf(v0.z); sv[3] = (short)f2bf(v0.w);
            sv[4] = (short)f2bf(v1.x); sv[5] = (short)f2bf(v1.y);
            sv[6] = (short)f2bf(v1.z); sv[7] = (short)f2bf(v1.w);
            *(short8*)&lsA[orow * 40 + kc * 8] = sv;
        }
        // stage B transposed [p][k]: t1 on the fly
        {
            int kg = k0 + kl;
            int c1 = kg / 3, tap = kg - c1 * 3, off = 2 * tap - 2;
            const float* xr = xb + (size_t)c1 * HW;
            #pragma unroll
            for (int j = 0; j < 8; ++j) {
                int pl = pg * 8 + j;
                int p = p0 + pl;
                int w = p % WW;
                float xv = ((unsigned)(w + off) < (unsigned)WW) ? xr[p + off] : 0.0f;
                lsB[pl * 40 + kl] = f2bf(xv);
            }
        }
        __syncthreads();
        short8 af[4], bfr[4];
        #pragma unroll
        for (int i = 0; i < 4; ++i)
            af[i] = *(const short8*)&lsA[(wid * 64 + i * 16 + l15) * 40 + l16 * 8];
        #pragma unroll
        for (int j = 0; j < 4; ++j)
            bfr[j] = *(const short8*)&lsB[(j * 16 + l15) * 40 + l16 * 8];
        #pragma unroll
        for (int i = 0; i < 4; ++i)
            #pragma unroll
            for (int j = 0; j < 4; ++j)
                acc[i][j] = __builtin_amdgcn_mfma_f32_16x16x32_bf16(af[i], bfr[j], acc[i][j], 0, 0, 0);
        __syncthreads();
    }
    // write t3 tile to LDS (bf16)
    #pragma unroll
    for (int i = 0; i < 4; ++i)
        #pragma unroll
        for (int j = 0; j < 4; ++j)
            #pragma unroll
            for (int r = 0; r < 4; ++r) {
                int o = wid * 64 + i * 16 + (l16 << 2) + r;
                int pl = j * 16 + l15;
                t3t[o * T3S + pl] = f2bf(acc[i][j][r]);
            }
    __syncthreads();

    // ---------------- phase 2: output tile ----------------
    #pragma unroll
    for (int i = 0; i < 4; ++i)
        #pragma unroll
        for (int j = 0; j < 4; ++j)
            acc[i][j] = (f32x4){0.f, 0.f, 0.f, 0.f};

    const u16* t7b = t7t + (size_t)b * CC * K3;

    for (int k0 = 0; k0 < K3; k0 += 32) {
        // stage A: t7t (256 rows x 32 k), bf16 direct copy
        #pragma unroll
        for (int cc = 0; cc < 4; ++cc) {
            int ch = t + cc * 256;
            int crow = ch >> 2, kc = ch & 3;
            const uint4 v = *(const uint4*)(t7b + (size_t)crow * K3 + k0 + kc * 8);
            *(uint4*)&lsA[crow * 40 + kc * 8] = v;
        }
        // stage B transposed [p][k]: t6 on the fly
        {
            int kg = k0 + kl;
            int c1 = kg / 3, tap = kg - c1 * 3, off = 2 * tap - 2;
            const float* xr = xb + (size_t)c1 * HW;
            #pragma unroll
            for (int j = 0; j < 8; ++j) {
                int pl = pg * 8 + j;
                int p = p0 + pl;
                int w = p % WW;
                float xv = ((unsigned)(w + off) < (unsigned)WW) ? xr[p + off] : 0.0f;
                float t4v = sinf(1.5707963f * xv);
                float bv = fmaxf(bf2f(t3t[c1 * T3S + pl]), t4v);
                lsB[pl * 40 + kl] = f2bf(bv);
            }
        }
        __syncthreads();
        short8 af[4], bfr[4];
        #pragma unroll
        for (int i = 0; i < 4; ++i)
            af[i] = *(const short8*)&lsA[(wid * 64 + i * 16 + l15) * 40 + l16 * 8];
        #pragma unroll
        for (int j = 0; j < 4; ++j)
            bfr[j] = *(const short8*)&lsB[(j * 16 + l15) * 40 + l16 * 8];
        #pragma unroll
        for (int i = 0; i < 4; ++i)
            #pragma unroll
            for (int j = 0; j < 4; ++j)
                acc[i][j] = __builtin_amdgcn_mfma_f32_16x16x32_bf16(af[i], bfr[j], acc[i][j], 0, 0, 0);
        __syncthreads();
    }

    const float s = 0.03608439182435161f;   // 1/sqrt(768)
    #pragma unroll
    for (int i = 0; i < 4; ++i)
        #pragma unroll
        for (int j = 0; j < 4; ++j)
            #pragma unroll
            for (int r = 0; r < 4; ++r) {
                int c2 = wid * 64 + i * 16 + (l16 << 2) + r;
                int p = p0 + j * 16 + l15;
                out[((size_t)b * CC + c2) * HW + p] = acc[i][j][r] * s;   // FLOAT32
            }
}

extern "C" void kernel_launch(void* const* d_in, const int* in_sizes, int n_in,
                              void* d_out, int out_size, void* d_ws, size_t ws_size,
                              hipStream_t stream) {
    const float* x   = (const float*)d_in[0];   // (16,256,56,56) f32
    const float* w3  = (const float*)d_in[1];   // (256,768) f32
    const float* p7  = (const float*)d_in[2];   // (1,256,3,256) f32
    float* out = (float*)d_out;                 // FLOAT32 output

    u16* t7t = (u16*)d_ws;                      // 16*256*768 bf16 = 6.3 MB

    k1_t7<<<dim3(6, 2, 16), 256, 0, stream>>>(x, p7, t7t);
    k23_fused<<<dim3(49, 16), 256, 0, stream>>>(x, w3, t7t, out);
}